// Round 2
// baseline (100.585 us; speedup 1.0000x reference)
//
#include <hip/hip_runtime.h>

// GetCost: per-pixel inverse-depth resampling of depth-plane profiles.
// Inputs (setup_inputs order):
//   d_in[0] depth_values   (B,1,H,W) f32
//   d_in[1] pro0           (B*H*W, G=8, D=32) f32
//   d_in[2] pro1           (B*H*W, 1,   D=32) f32
//   d_in[3] depth_interval (B,1,H,W) f32
//   d_in[4] CostNum        (1,) int  -- derived on host from out_size instead
// Output: (B, (G+1)*ND, H, W) f32, sim channels first then corr.
//
// R1: split work across grid.y = G+1 rows (one thread per (pixel,row)).
// Each 128B profile row is still read by exactly one thread (no duplicated
// HBM fetch), but wave count goes 2560 -> 23040, hiding gather latency.

static constexpr int   HW_  = 256 * 320;   // 81920
static constexpr int   DPL  = 32;          // depth planes
static constexpr float DMIN = 425.0f;
static constexpr float DMAX = 935.0f;

template <int ND>
__global__ __launch_bounds__(256)
void getcost_rows(const float* __restrict__ dv,
                  const float* __restrict__ pro0,
                  const float* __restrict__ pro1,
                  const float* __restrict__ di,
                  float* __restrict__ out,
                  int npix, int grp)
{
    int p = blockIdx.x * blockDim.x + threadIdx.x;
    int r = blockIdx.y;                 // 0 = sim (pro1), 1..grp = corr group r-1
    if (p >= npix) return;
    int b  = p / HW_;
    int hw = p - b * HW_;

    const float inv_min = (float)(1.0 / (double)DMAX);
    const float inv_max = (float)(1.0 / (double)DMIN);
    const float denom   = (inv_max - inv_min) + 1e-10f;

    float cur = 1.0f / dv[p];
    float itv = di[p];
    const float ndf = (float)ND;
    float low     = cur - (ndf * 0.5f) * itv;
    float new_itv = (ndf * itv) / (ndf - 1.0f);

    int   i0c[ND], i1c[ND];
    float w0v[ND], w1v[ND];
    bool  v0v[ND], v1v[ND];

#pragma unroll
    for (int j = 0; j < ND; ++j) {
        float samp_inv = low + (float)j * new_itv;
        float dsamp    = 1.0f / samp_inv;            // reference: 1/samp_inv
        float x = (1.0f / dsamp - inv_min) / denom * (float)(DPL - 1);
        float x0 = floorf(x);
        float w1 = x - x0;
        float x1 = x0 + 1.0f;
        v0v[j] = (x0 >= 0.0f) && (x0 <= (float)(DPL - 1));
        v1v[j] = (x1 >= 0.0f) && (x1 <= (float)(DPL - 1));
        i0c[j] = (int)fminf(fmaxf(x0, 0.0f), (float)(DPL - 1));
        i1c[j] = (int)fminf(fmaxf(x1, 0.0f), (float)(DPL - 1));
        w1v[j] = w1;
        w0v[j] = 1.0f - w1;
    }

    // Row selection is wave-uniform (blockIdx.y).
    const float* __restrict__ row =
        (r == 0) ? pro1 + (size_t)p * DPL
                 : pro0 + ((size_t)p * grp + (r - 1)) * DPL;

    // Output channel for (r, j) is r*ND + j  (sim first, then corr groups).
    float* __restrict__ outp =
        out + ((size_t)b * (grp + 1) * ND + (size_t)r * ND) * HW_ + hw;

#pragma unroll
    for (int j = 0; j < ND; ++j) {
        float a = v0v[j] ? row[i0c[j]] : 0.0f;
        float c = v1v[j] ? row[i1c[j]] : 0.0f;
        outp[(size_t)j * HW_] = a * w0v[j] + c * w1v[j];
    }
}

// Generic fallback for unexpected ND (runtime loop, no per-thread arrays).
__global__ __launch_bounds__(256)
void getcost_rows_generic(const float* __restrict__ dv,
                          const float* __restrict__ pro0,
                          const float* __restrict__ pro1,
                          const float* __restrict__ di,
                          float* __restrict__ out,
                          int npix, int grp, int nd)
{
    int p = blockIdx.x * blockDim.x + threadIdx.x;
    int r = blockIdx.y;
    if (p >= npix) return;
    int b  = p / HW_;
    int hw = p - b * HW_;

    const float inv_min = (float)(1.0 / (double)DMAX);
    const float inv_max = (float)(1.0 / (double)DMIN);
    const float denom   = (inv_max - inv_min) + 1e-10f;

    float cur = 1.0f / dv[p];
    float itv = di[p];
    float ndf = (float)nd;
    float low     = cur - (ndf * 0.5f) * itv;
    float new_itv = (ndf * itv) / (ndf - 1.0f);

    const float* row =
        (r == 0) ? pro1 + (size_t)p * DPL
                 : pro0 + ((size_t)p * grp + (r - 1)) * DPL;
    float* outp =
        out + ((size_t)b * (grp + 1) * nd + (size_t)r * nd) * HW_ + hw;

    for (int j = 0; j < nd; ++j) {
        float samp_inv = low + (float)j * new_itv;
        float dsamp    = 1.0f / samp_inv;
        float x = (1.0f / dsamp - inv_min) / denom * (float)(DPL - 1);
        float x0 = floorf(x);
        float w1 = x - x0;
        float x1 = x0 + 1.0f;
        bool v0 = (x0 >= 0.0f) && (x0 <= (float)(DPL - 1));
        bool v1 = (x1 >= 0.0f) && (x1 <= (float)(DPL - 1));
        int i0 = (int)fminf(fmaxf(x0, 0.0f), (float)(DPL - 1));
        int i1 = (int)fminf(fmaxf(x1, 0.0f), (float)(DPL - 1));
        float w0 = 1.0f - w1;

        float a = v0 ? row[i0] : 0.0f;
        float c = v1 ? row[i1] : 0.0f;
        outp[(size_t)j * HW_] = a * w0 + c * w1;
    }
}

extern "C" void kernel_launch(void* const* d_in, const int* in_sizes, int n_in,
                              void* d_out, int out_size, void* d_ws, size_t ws_size,
                              hipStream_t stream) {
    const float* dv   = (const float*)d_in[0];
    const float* pro0 = (const float*)d_in[1];
    const float* pro1 = (const float*)d_in[2];
    const float* di   = (const float*)d_in[3];
    float* out = (float*)d_out;

    int npix = in_sizes[0];                        // B*1*H*W
    int grp  = in_sizes[1] / (npix * DPL);         // pro0 groups (8)
    int nd   = out_size / (npix * (grp + 1));      // CostNum (4), derived on host

    int threads = 256;
    dim3 grid((npix + threads - 1) / threads, grp + 1);

    if (nd == 4) {
        getcost_rows<4><<<grid, threads, 0, stream>>>(dv, pro0, pro1, di, out, npix, grp);
    } else {
        getcost_rows_generic<<<grid, threads, 0, stream>>>(dv, pro0, pro1, di, out, npix, grp, nd);
    }
}

// Round 3
// 37.585 us; speedup vs baseline: 2.6762x; 2.6762x over previous
//
#include <hip/hip_runtime.h>

// GetCost: per-pixel inverse-depth resampling of depth-plane profiles.
// Inputs (setup_inputs order):
//   d_in[0] depth_values   (B,1,H,W) f32
//   d_in[1] pro0           (B*H*W, G=8, D=32) f32
//   d_in[2] pro1           (B*H*W, 1,   D=32) f32
//   d_in[3] depth_interval (B,1,H,W) f32
//   d_in[4] CostNum        (1,) int  -- derived on host from out_size instead
// Output: (B, (G+1)*ND, H, W) f32, sim channels first then corr.
//
// R2: keep R1's high occupancy (1 thread per (pixel,row)) but consume each
// 128B profile row in ONE burst: the 8 gather elements always fall in 4
// consecutive planes [s,s+3] (sample window spans <1.5 planes), so issue 4
// independent scalar loads (MSHR-merge into one line fetch) and select in
// registers. Guarded per-lane fallback load keeps arbitrary inputs correct.
// Lane swizzle: lanes 0..7 = the 8 groups of one pixel (8KiB/wave footprint).

static constexpr int   HW_  = 256 * 320;   // 81920
static constexpr int   DPL  = 32;          // depth planes
static constexpr float DMIN = 425.0f;
static constexpr float DMAX = 935.0f;

template <int ND, int GRP>
__global__ __launch_bounds__(256)
void getcost_win(const float* __restrict__ dv,
                 const float* __restrict__ pro0,
                 const float* __restrict__ pro1,
                 const float* __restrict__ di,
                 float* __restrict__ out,
                 int npix)
{
    const long long tid   = (long long)blockIdx.x * blockDim.x + threadIdx.x;
    const long long ncorr = (long long)npix * GRP;

    int p, r;                      // pixel, output row (0=sim, 1..GRP=corr g+1)
    const float* __restrict__ row;
    if (tid < ncorr) {
        p = (int)(tid >> 3);       // GRP == 8
        int g = (int)(tid & (GRP - 1));
        r = g + 1;
        row = pro0 + ((size_t)p * GRP + g) * DPL;
    } else {
        p = (int)(tid - ncorr);
        if (p >= npix) return;
        r = 0;
        row = pro1 + (size_t)p * DPL;
    }

    const int b  = p / HW_;
    const int hw = p - b * HW_;

    const float inv_min = (float)(1.0 / (double)DMAX);
    const float inv_max = (float)(1.0 / (double)DMIN);
    const float denom   = (inv_max - inv_min) + 1e-10f;

    const float cur = 1.0f / dv[p];
    const float itv = di[p];
    const float ndf = (float)ND;
    const float low     = cur - (ndf * 0.5f) * itv;
    const float new_itv = (ndf * itv) / (ndf - 1.0f);

    int   i0c[ND], i1c[ND];
    float w0v[ND], w1v[ND];
    bool  v0v[ND], v1v[ND];

#pragma unroll
    for (int j = 0; j < ND; ++j) {
        float samp_inv = low + (float)j * new_itv;
        float dsamp    = 1.0f / samp_inv;            // reference: 1/samp_inv
        float x = (1.0f / dsamp - inv_min) / denom * (float)(DPL - 1);
        float x0 = floorf(x);
        float w1 = x - x0;
        float x1 = x0 + 1.0f;
        v0v[j] = (x0 >= 0.0f) && (x0 <= (float)(DPL - 1));
        v1v[j] = (x1 >= 0.0f) && (x1 <= (float)(DPL - 1));
        i0c[j] = (int)fminf(fmaxf(x0, 0.0f), (float)(DPL - 1));
        i1c[j] = (int)fminf(fmaxf(x1, 0.0f), (float)(DPL - 1));
        w1v[j] = w1;
        w0v[j] = 1.0f - w1;
    }

    // Burst-load the 4-plane window covering all samples (indices are
    // nondecreasing in j and span < 4 planes for real data).
    const int s = min(i0c[0], DPL - 4);
    float wv[4];
#pragma unroll
    for (int k = 0; k < 4; ++k) wv[k] = row[s + k];

    float* __restrict__ outp =
        out + ((size_t)b * (GRP + 1) * ND + (size_t)r * ND) * HW_ + hw;

#pragma unroll
    for (int j = 0; j < ND; ++j) {
        int r0 = i0c[j] - s;
        int r1 = i1c[j] - s;
        float a = (r0 >= 0 && r0 < 4)
                    ? (r0 == 0 ? wv[0] : r0 == 1 ? wv[1] : r0 == 2 ? wv[2] : wv[3])
                    : row[i0c[j]];                    // guarded fallback (rare)
        float c = (r1 >= 0 && r1 < 4)
                    ? (r1 == 0 ? wv[0] : r1 == 1 ? wv[1] : r1 == 2 ? wv[2] : wv[3])
                    : row[i1c[j]];                    // guarded fallback (rare)
        a = v0v[j] ? a : 0.0f;
        c = v1v[j] ? c : 0.0f;
        outp[(size_t)j * HW_] = a * w0v[j] + c * w1v[j];
    }
}

// Generic fallback for unexpected ND / G (runtime loops, no per-thread arrays).
__global__ __launch_bounds__(256)
void getcost_rows_generic(const float* __restrict__ dv,
                          const float* __restrict__ pro0,
                          const float* __restrict__ pro1,
                          const float* __restrict__ di,
                          float* __restrict__ out,
                          int npix, int grp, int nd)
{
    int p = blockIdx.x * blockDim.x + threadIdx.x;
    int r = blockIdx.y;
    if (p >= npix) return;
    int b  = p / HW_;
    int hw = p - b * HW_;

    const float inv_min = (float)(1.0 / (double)DMAX);
    const float inv_max = (float)(1.0 / (double)DMIN);
    const float denom   = (inv_max - inv_min) + 1e-10f;

    float cur = 1.0f / dv[p];
    float itv = di[p];
    float ndf = (float)nd;
    float low     = cur - (ndf * 0.5f) * itv;
    float new_itv = (ndf * itv) / (ndf - 1.0f);

    const float* row =
        (r == 0) ? pro1 + (size_t)p * DPL
                 : pro0 + ((size_t)p * grp + (r - 1)) * DPL;
    float* outp =
        out + ((size_t)b * (grp + 1) * nd + (size_t)r * nd) * HW_ + hw;

    for (int j = 0; j < nd; ++j) {
        float samp_inv = low + (float)j * new_itv;
        float dsamp    = 1.0f / samp_inv;
        float x = (1.0f / dsamp - inv_min) / denom * (float)(DPL - 1);
        float x0 = floorf(x);
        float w1 = x - x0;
        float x1 = x0 + 1.0f;
        bool v0 = (x0 >= 0.0f) && (x0 <= (float)(DPL - 1));
        bool v1 = (x1 >= 0.0f) && (x1 <= (float)(DPL - 1));
        int i0 = (int)fminf(fmaxf(x0, 0.0f), (float)(DPL - 1));
        int i1 = (int)fminf(fmaxf(x1, 0.0f), (float)(DPL - 1));
        float w0 = 1.0f - w1;

        float a = v0 ? row[i0] : 0.0f;
        float c = v1 ? row[i1] : 0.0f;
        outp[(size_t)j * HW_] = a * w0 + c * w1;
    }
}

extern "C" void kernel_launch(void* const* d_in, const int* in_sizes, int n_in,
                              void* d_out, int out_size, void* d_ws, size_t ws_size,
                              hipStream_t stream) {
    const float* dv   = (const float*)d_in[0];
    const float* pro0 = (const float*)d_in[1];
    const float* pro1 = (const float*)d_in[2];
    const float* di   = (const float*)d_in[3];
    float* out = (float*)d_out;

    int npix = in_sizes[0];                        // B*1*H*W
    int grp  = in_sizes[1] / (npix * DPL);         // pro0 groups (8)
    int nd   = out_size / (npix * (grp + 1));      // CostNum (4), derived on host

    if (nd == 4 && grp == 8) {
        long long total = (long long)npix * (grp + 1);
        int threads = 256;
        int blocks  = (int)((total + threads - 1) / threads);
        getcost_win<4, 8><<<blocks, threads, 0, stream>>>(dv, pro0, pro1, di, out, npix);
    } else {
        int threads = 256;
        dim3 grid((npix + threads - 1) / threads, grp + 1);
        getcost_rows_generic<<<grid, threads, 0, stream>>>(dv, pro0, pro1, di, out, npix, grp, nd);
    }
}

// Round 4
// 37.325 us; speedup vs baseline: 2.6948x; 1.0070x over previous
//
#include <hip/hip_runtime.h>

// GetCost: per-pixel inverse-depth resampling of depth-plane profiles.
// Inputs (setup_inputs order):
//   d_in[0] depth_values   (B,1,H,W) f32
//   d_in[1] pro0           (B*H*W, G=8, D=32) f32
//   d_in[2] pro1           (B*H*W, 1,   D=32) f32
//   d_in[3] depth_interval (B,1,H,W) f32
//   d_in[4] CostNum        (1,) int  -- derived on host from out_size instead
// Output: (B, (G+1)*ND, H, W) f32, sim channels first then corr.
//
// R3: R1's mapping (grid.y = row, lanes = consecutive pixels -> 256B
// coalesced writes, contiguous pro1 reads) + R2's burst-window consumption,
// upgraded to two ALIGNED float4 loads covering the sample window.
// Each 128B profile row (one L2 line) is consumed by one thread in one
// back-to-back vector-load burst -> fetched exactly once (R1's refetch
// pathology structurally impossible). Guarded per-lane fallback load keeps
// arbitrary inputs correct.

static constexpr int   HW_  = 256 * 320;   // 81920
static constexpr int   DPL  = 32;          // depth planes
static constexpr float DMIN = 425.0f;
static constexpr float DMAX = 935.0f;

template <int ND>
__global__ __launch_bounds__(256)
void getcost_win2(const float* __restrict__ dv,
                  const float* __restrict__ pro0,
                  const float* __restrict__ pro1,
                  const float* __restrict__ di,
                  float* __restrict__ out,
                  int npix, int grp)
{
    const int p = blockIdx.x * blockDim.x + threadIdx.x;
    const int r = blockIdx.y;          // 0 = sim (pro1), 1..grp = corr group r-1
    if (p >= npix) return;
    const int b  = p / HW_;
    const int hw = p - b * HW_;

    const float inv_min = (float)(1.0 / (double)DMAX);
    const float inv_max = (float)(1.0 / (double)DMIN);
    const float denom   = (inv_max - inv_min) + 1e-10f;

    const float cur = 1.0f / dv[p];
    const float itv = di[p];
    const float ndf = (float)ND;
    const float low     = cur - (ndf * 0.5f) * itv;
    const float new_itv = (ndf * itv) / (ndf - 1.0f);

    int   i0c[ND], i1c[ND];
    float w0v[ND], w1v[ND];
    bool  v0v[ND], v1v[ND];

#pragma unroll
    for (int j = 0; j < ND; ++j) {
        float samp_inv = low + (float)j * new_itv;
        float dsamp    = 1.0f / samp_inv;            // reference: 1/samp_inv
        float x = (1.0f / dsamp - inv_min) / denom * (float)(DPL - 1);
        float x0 = floorf(x);
        float w1 = x - x0;
        float x1 = x0 + 1.0f;
        v0v[j] = (x0 >= 0.0f) && (x0 <= (float)(DPL - 1));
        v1v[j] = (x1 >= 0.0f) && (x1 <= (float)(DPL - 1));
        i0c[j] = (int)fminf(fmaxf(x0, 0.0f), (float)(DPL - 1));
        i1c[j] = (int)fminf(fmaxf(x1, 0.0f), (float)(DPL - 1));
        w1v[j] = w1;
        w0v[j] = 1.0f - w1;
    }

    // Row selection is wave-uniform (blockIdx.y).
    const float* __restrict__ row =
        (r == 0) ? pro1 + (size_t)p * DPL
                 : pro0 + ((size_t)p * grp + (r - 1)) * DPL;

    // Aligned 8-float window [s4, s4+7] covering all samples [s, s+3].
    // s <= 28, s4 = min(s & ~3, 24)  =>  s - s4 <= 4, so s+3 <= s4+7 <= 31.
    const int s  = min(i0c[0], DPL - 4);
    const int s4 = min(s & ~3, DPL - 8);
    const float4 wa = *reinterpret_cast<const float4*>(row + s4);
    const float4 wb = *reinterpret_cast<const float4*>(row + s4 + 4);
    const float wv[8] = {wa.x, wa.y, wa.z, wa.w, wb.x, wb.y, wb.z, wb.w};

    float* __restrict__ outp =
        out + ((size_t)b * (grp + 1) * ND + (size_t)r * ND) * HW_ + hw;

#pragma unroll
    for (int j = 0; j < ND; ++j) {
        const int r0 = i0c[j] - s4;
        const int r1 = i1c[j] - s4;
        float a, c;
        if (r0 >= 0 && r0 < 8) {      // in-window: unrolled cndmask select
            a = wv[0];
#pragma unroll
            for (int k = 1; k < 8; ++k) a = (r0 == k) ? wv[k] : a;
        } else {
            a = row[i0c[j]];          // guarded fallback (never for real data)
        }
        if (r1 >= 0 && r1 < 8) {
            c = wv[0];
#pragma unroll
            for (int k = 1; k < 8; ++k) c = (r1 == k) ? wv[k] : c;
        } else {
            c = row[i1c[j]];
        }
        a = v0v[j] ? a : 0.0f;
        c = v1v[j] ? c : 0.0f;
        outp[(size_t)j * HW_] = a * w0v[j] + c * w1v[j];
    }
}

// Generic fallback for unexpected ND / G (runtime loops, no per-thread arrays).
__global__ __launch_bounds__(256)
void getcost_rows_generic(const float* __restrict__ dv,
                          const float* __restrict__ pro0,
                          const float* __restrict__ pro1,
                          const float* __restrict__ di,
                          float* __restrict__ out,
                          int npix, int grp, int nd)
{
    int p = blockIdx.x * blockDim.x + threadIdx.x;
    int r = blockIdx.y;
    if (p >= npix) return;
    int b  = p / HW_;
    int hw = p - b * HW_;

    const float inv_min = (float)(1.0 / (double)DMAX);
    const float inv_max = (float)(1.0 / (double)DMIN);
    const float denom   = (inv_max - inv_min) + 1e-10f;

    float cur = 1.0f / dv[p];
    float itv = di[p];
    float ndf = (float)nd;
    float low     = cur - (ndf * 0.5f) * itv;
    float new_itv = (ndf * itv) / (ndf - 1.0f);

    const float* row =
        (r == 0) ? pro1 + (size_t)p * DPL
                 : pro0 + ((size_t)p * grp + (r - 1)) * DPL;
    float* outp =
        out + ((size_t)b * (grp + 1) * nd + (size_t)r * nd) * HW_ + hw;

    for (int j = 0; j < nd; ++j) {
        float samp_inv = low + (float)j * new_itv;
        float dsamp    = 1.0f / samp_inv;
        float x = (1.0f / dsamp - inv_min) / denom * (float)(DPL - 1);
        float x0 = floorf(x);
        float w1 = x - x0;
        float x1 = x0 + 1.0f;
        bool v0 = (x0 >= 0.0f) && (x0 <= (float)(DPL - 1));
        bool v1 = (x1 >= 0.0f) && (x1 <= (float)(DPL - 1));
        int i0 = (int)fminf(fmaxf(x0, 0.0f), (float)(DPL - 1));
        int i1 = (int)fminf(fmaxf(x1, 0.0f), (float)(DPL - 1));
        float w0 = 1.0f - w1;

        float a = v0 ? row[i0] : 0.0f;
        float c = v1 ? row[i1] : 0.0f;
        outp[(size_t)j * HW_] = a * w0 + c * w1;
    }
}

extern "C" void kernel_launch(void* const* d_in, const int* in_sizes, int n_in,
                              void* d_out, int out_size, void* d_ws, size_t ws_size,
                              hipStream_t stream) {
    const float* dv   = (const float*)d_in[0];
    const float* pro0 = (const float*)d_in[1];
    const float* pro1 = (const float*)d_in[2];
    const float* di   = (const float*)d_in[3];
    float* out = (float*)d_out;

    int npix = in_sizes[0];                        // B*1*H*W
    int grp  = in_sizes[1] / (npix * DPL);         // pro0 groups (8)
    int nd   = out_size / (npix * (grp + 1));      // CostNum (4), derived on host

    int threads = 256;
    dim3 grid((npix + threads - 1) / threads, grp + 1);

    if (nd == 4) {
        getcost_win2<4><<<grid, threads, 0, stream>>>(dv, pro0, pro1, di, out, npix, grp);
    } else {
        getcost_rows_generic<<<grid, threads, 0, stream>>>(dv, pro0, pro1, di, out, npix, grp, nd);
    }
}